// Round 1
// 512.922 us; speedup vs baseline: 1.0333x; 1.0333x over previous
//
#include <hip/hip_runtime.h>
#include <hip/hip_bf16.h>
#include <math.h>

typedef short short8 __attribute__((ext_vector_type(8)));
typedef float f32x4 __attribute__((ext_vector_type(4)));

__device__ __forceinline__ unsigned short f2bf(float x) {
    unsigned u = __float_as_uint(x);
    u += 0x7FFF + ((u >> 16) & 1);   // RNE
    return (unsigned short)(u >> 16);
}
__device__ __forceinline__ float bf2f(unsigned short h) {
    return __uint_as_float(((unsigned)h) << 16);
}

// Dekker-style split of 2 floats into packed bf16 hi words + bf16 lo words.
// hi = RNE bf16 of f (packed pair), residual r = f - hi is EXACT in fp32,
// lo = RNE bf16 of r.  6 VALU per pair.
__device__ __forceinline__ void cvtpair(float f0, float f1, unsigned& hw, unsigned& lw) {
    __hip_bfloat162 h2 = __float22bfloat162_rn(float2{f0, f1});
    unsigned hu = *(unsigned*)&h2;
    float r0 = f0 - __uint_as_float(hu << 16);
    float r1 = f1 - __uint_as_float(hu & 0xFFFF0000u);
    __hip_bfloat162 l2 = __float22bfloat162_rn(float2{r0, r1});
    hw = hu;
    lw = *(unsigned*)&l2;
}

__device__ __forceinline__ void cvt8(const float4 a, const float4 b, short8& hi, short8& lo) {
    union { unsigned u[4]; short8 s; } H, L;
    cvtpair(a.x, a.y, H.u[0], L.u[0]);
    cvtpair(a.z, a.w, H.u[1], L.u[1]);
    cvtpair(b.x, b.y, H.u[2], L.u[2]);
    cvtpair(b.z, b.w, H.u[3], L.u[3]);
    hi = H.s; lo = L.s;
}

__device__ __forceinline__ float tanh10(float y) {
    float e = __expf(2.f * y);
    return 10.f * (e - 1.f) / (e + 1.f);
}

#define GLDS16(gp, lp)                                                        \
    __builtin_amdgcn_global_load_lds(                                         \
        (const __attribute__((address_space(1))) void*)(gp),                  \
        (__attribute__((address_space(3))) void*)(lp), 16, 0, 0)

// ---------------------------------------------------------------------------
// K0: prep — Wt (fp32 transpose) + bf16 hi/lo split of W (row-major d x k),
// with the k-slot XOR swizzle PRE-APPLIED in global memory so that the linear
// global_load_lds staging in k_edge_mfma lands a bank-conflict-free layout:
//   phys_slot = slot ^ ((d>>1)&3), slot = 16B granule within each 32-k chunk.
// ---------------------------------------------------------------------------
__global__ __launch_bounds__(256) void k_prep(const float* __restrict__ W,
                                              float* __restrict__ Wt,
                                              unsigned short* __restrict__ Whi,
                                              unsigned short* __restrict__ Wlo) {
    int d = blockIdx.x, k = threadIdx.x;
    float w = W[d * 256 + k];
    Wt[k * 256 + d] = w;
    unsigned short hi = f2bf(w);
    int s  = (k >> 3) & 3;
    int sp = s ^ ((d >> 1) & 3);
    int idx = d * 256 + (k & ~31) + sp * 8 + (k & 7);
    Whi[idx] = hi;
    Wlo[idx] = f2bf(w - bf2f(hi));
}

// ---------------------------------------------------------------------------
// K1: node projection, 8-way acc split (unchanged)
// ---------------------------------------------------------------------------
__global__ __launch_bounds__(256) void k_node_proj(const float* __restrict__ nodes,
                                                   const float* __restrict__ Wt,
                                                   const float* __restrict__ bias,
                                                   float* __restrict__ np_) {
    int row = blockIdx.x;
    int d = threadIdx.x;
    __shared__ float xl[256];
    xl[d] = nodes[row * 256 + d];
    __syncthreads();
    float a[8] = {0.f, 0.f, 0.f, 0.f, 0.f, 0.f, 0.f, 0.f};
#pragma unroll 4
    for (int k = 0; k < 256; k += 8) {
#pragma unroll
        for (int q = 0; q < 8; ++q)
            a[q] = fmaf(xl[k + q], Wt[(k + q) * 256 + d], a[q]);
    }
    np_[row * 256 + d] =
        bias[d] + ((a[0] + a[1]) + (a[2] + a[3])) + ((a[4] + a[5]) + (a[6] + a[7]));
}

// ---------------------------------------------------------------------------
// K2: MFMA edge scores, register-staged A (no E LDS round-trip).
//   Block = 128 edges x 128 dims (4 heads).  grid = 4096 (2048 tiles x 2 halves).
//   Wave w owns edge rows [w*32, w*32+32), sweeps all 8 nt columns.
//   A: global->reg (float4 x4 per chunk per lane) -> Dekker bf16 hi/lo frags.
//   W: global_load_lds, double-buffered, source pre-swizzled by k_prep ->
//      2-way (free) ds_read_b128 bank pattern.
//   ONE __syncthreads per K-chunk, AFTER the MFMA phase: its vmcnt(0) drain
//   lands where prefetch latency is already covered by ~900cy of MFMA.
//   acc = Eh*Wh + Eh*Wl + El*Wh  (fp32 acc; dropped El*Wl ~2^-17 rel).
// ---------------------------------------------------------------------------
__global__ __launch_bounds__(256) void k_edge_mfma(const float* __restrict__ edges,
                                                   const unsigned short* __restrict__ Whi,
                                                   const unsigned short* __restrict__ Wlo,
                                                   const float* __restrict__ bias,
                                                   const float* __restrict__ np_,
                                                   float* __restrict__ attn) {
    __shared__ unsigned short Wbuf[2][2][128 * 32];  // [dbuf][hi/lo], 32 KB
    __shared__ float npi[128];
    __shared__ float sc[4][128];

    const int t = threadIdx.x;
    const int w = t >> 6, l = t & 63;

    // XCD-paired logical block id: pair (2k,2k+1) maps to phys ids 8 apart
    // (same XCD under %8 dispatch) and each XCD walks a contiguous tile range.
    const int L = (blockIdx.x & 7) * 512 + (blockIdx.x >> 3);
    const int tile = L >> 1, half = L & 1;
    const int m0 = tile * 128;             // first edge flat index
    const int bb = m0 >> 16;
    const int ii = (m0 >> 8) & 255;
    const int j0 = m0 & 255;               // 0 or 128
    const int n0 = half * 128;             // dim offset (heads 4*half..4*half+3)

    const int col = l & 15, g = l >> 4;
    const int wrow = l >> 2, wq = l & 3;   // W staging lane mapping

    if (t < 32)
        ((float4*)npi)[t] = ((const float4*)(np_ + (size_t)(bb * 256 + ii) * 256 + n0))[t];

    f32x4 acc[2][8];
#pragma unroll
    for (int mt = 0; mt < 2; ++mt)
#pragma unroll
        for (int nt = 0; nt < 8; ++nt) acc[mt][nt] = (f32x4){0.f, 0.f, 0.f, 0.f};

    // Per-lane A base pointers: rows w*32 + mt*16 + col, k-slice g*8
    const float* ea0 = edges + (size_t)(m0 + w * 32 + col) * 256 + g * 8;
    const float* ea1 = ea0 + 16 * 256;

    // W staging global offsets (row part); source is pre-swizzled
    const size_t wg0 = (size_t)(n0 + w * 32 + wrow) * 256 + wq * 8;
    const size_t wg1 = wg0 + 16 * 256;

    // ---- prologue: A(0) loads + W(0) stage + convert
    float4 e0a = *(const float4*)(ea0);
    float4 e0b = *(const float4*)(ea0 + 4);
    float4 e1a = *(const float4*)(ea1);
    float4 e1b = *(const float4*)(ea1 + 4);
    GLDS16(Whi + wg0, &Wbuf[0][0][(w * 32) * 32]);
    GLDS16(Wlo + wg0, &Wbuf[0][1][(w * 32) * 32]);
    GLDS16(Whi + wg1, &Wbuf[0][0][(w * 32 + 16) * 32]);
    GLDS16(Wlo + wg1, &Wbuf[0][1][(w * 32 + 16) * 32]);

    short8 Ah[2], Al[2];
    cvt8(e0a, e0b, Ah[0], Al[0]);
    cvt8(e1a, e1b, Ah[1], Al[1]);
    __syncthreads();   // implicit vmcnt(0): W(0) landed for all waves

    // swizzled B read base: slot' = g ^ ((r>>1)&3); nt-part (nt*16) is 0 mod 4
    // so the XOR term depends only on col -> one base + immediate offsets.
    const int swb = (g ^ ((col >> 1) & 3)) << 3;

#pragma unroll 2
    for (int kc = 0; kc < 8; ++kc) {
        float4 p0a, p0b, p1a, p1b;
        if (kc < 7) {
            const int nb = (kc + 1) & 1;
            const size_t kofs = (size_t)(kc + 1) * 32;
            GLDS16(Whi + wg0 + kofs, &Wbuf[nb][0][(w * 32) * 32]);
            GLDS16(Wlo + wg0 + kofs, &Wbuf[nb][1][(w * 32) * 32]);
            GLDS16(Whi + wg1 + kofs, &Wbuf[nb][0][(w * 32 + 16) * 32]);
            GLDS16(Wlo + wg1 + kofs, &Wbuf[nb][1][(w * 32 + 16) * 32]);
            p0a = *(const float4*)(ea0 + (kc + 1) * 32);
            p0b = *(const float4*)(ea0 + (kc + 1) * 32 + 4);
            p1a = *(const float4*)(ea1 + (kc + 1) * 32);
            p1b = *(const float4*)(ea1 + (kc + 1) * 32 + 4);
        }
        // ---- MFMA phase on buf[kc&1]
        const unsigned short* bh = &Wbuf[kc & 1][0][0] + col * 32 + swb;
        const unsigned short* bl = &Wbuf[kc & 1][1][0] + col * 32 + swb;
#pragma unroll
        for (int nt = 0; nt < 8; ++nt) {
            short8 Bh = *(const short8*)(bh + nt * 512);
            short8 Bl = *(const short8*)(bl + nt * 512);
            acc[0][nt] = __builtin_amdgcn_mfma_f32_16x16x32_bf16(Ah[0], Bh, acc[0][nt], 0, 0, 0);
            acc[1][nt] = __builtin_amdgcn_mfma_f32_16x16x32_bf16(Ah[1], Bh, acc[1][nt], 0, 0, 0);
            acc[0][nt] = __builtin_amdgcn_mfma_f32_16x16x32_bf16(Ah[0], Bl, acc[0][nt], 0, 0, 0);
            acc[1][nt] = __builtin_amdgcn_mfma_f32_16x16x32_bf16(Ah[1], Bl, acc[1][nt], 0, 0, 0);
            acc[0][nt] = __builtin_amdgcn_mfma_f32_16x16x32_bf16(Al[0], Bh, acc[0][nt], 0, 0, 0);
            acc[1][nt] = __builtin_amdgcn_mfma_f32_16x16x32_bf16(Al[1], Bh, acc[1][nt], 0, 0, 0);
        }
        // ---- convert next chunk (reg-dep wait drains ALL older vm ops,
        //      including this iter's W stage -> next iter's reads are safe)
        if (kc < 7) {
            cvt8(p0a, p0b, Ah[0], Al[0]);
            cvt8(p1a, p1b, Ah[1], Al[1]);
        }
        __syncthreads();   // single barrier per chunk, post-MFMA drain
    }

    // ---- epilogue: scores for the 4 heads of this half
    const float isq = 0.17677669529663687f;  // 1/sqrt(32)
    float bv[8], nv[8];
#pragma unroll
    for (int nt = 0; nt < 8; ++nt) {
        int dl = nt * 16 + col;
        bv[nt] = bias[n0 + dl];
        nv[nt] = npi[dl];
    }
#pragma unroll
    for (int mt = 0; mt < 2; ++mt) {
#pragma unroll
        for (int r = 0; r < 4; ++r) {
            int el = w * 32 + mt * 16 + g * 4 + r;   // 0..127 within tile
            int j = j0 + el;
            const float* npj = np_ + (size_t)(bb * 256 + j) * 256 + n0;
            float p, s0 = 0.f, s1 = 0.f, s2 = 0.f, s3 = 0.f;
            p = acc[mt][0][r] + bv[0]; s0 += (p + nv[0]) * (p + npj[col]);
            p = acc[mt][1][r] + bv[1]; s0 += (p + nv[1]) * (p + npj[16 + col]);
            p = acc[mt][2][r] + bv[2]; s1 += (p + nv[2]) * (p + npj[32 + col]);
            p = acc[mt][3][r] + bv[3]; s1 += (p + nv[3]) * (p + npj[48 + col]);
            p = acc[mt][4][r] + bv[4]; s2 += (p + nv[4]) * (p + npj[64 + col]);
            p = acc[mt][5][r] + bv[5]; s2 += (p + nv[5]) * (p + npj[80 + col]);
            p = acc[mt][6][r] + bv[6]; s3 += (p + nv[6]) * (p + npj[96 + col]);
            p = acc[mt][7][r] + bv[7]; s3 += (p + nv[7]) * (p + npj[112 + col]);
#pragma unroll
            for (int m = 1; m < 16; m <<= 1) {
                s0 += __shfl_xor(s0, m, 64);
                s1 += __shfl_xor(s1, m, 64);
                s2 += __shfl_xor(s2, m, 64);
                s3 += __shfl_xor(s3, m, 64);
            }
            if (col == 0) {
                sc[0][el] = tanh10(s0 * isq);
                sc[1][el] = tanh10(s1 * isq);
                sc[2][el] = tanh10(s2 * isq);
                sc[3][el] = tanh10(s3 * isq);
            }
        }
    }
    __syncthreads();
    if (t < 128) {
        int hl = t >> 5, q = t & 31;
        float4 v = *(float4*)&sc[hl][q * 4];
        *(float4*)(attn + (((size_t)(bb * 8 + half * 4 + hl) * 256 + ii) << 8) + j0 + q * 4) = v;
    }
}

// ---------------------------------------------------------------------------
// K3: softmax over j (rows of 256), one wave per row (unchanged)
// ---------------------------------------------------------------------------
__global__ __launch_bounds__(256) void k_softmax(float* __restrict__ attn) {
    int row = (blockIdx.x * 256 + threadIdx.x) >> 6;
    int lane = threadIdx.x & 63;
    float4* rowp = (float4*)(attn + (size_t)row * 256);
    float4 v = rowp[lane];
    float m = fmaxf(fmaxf(v.x, v.y), fmaxf(v.z, v.w));
#pragma unroll
    for (int s = 1; s < 64; s <<= 1) m = fmaxf(m, __shfl_xor(m, s, 64));
    v.x = __expf(v.x - m); v.y = __expf(v.y - m);
    v.z = __expf(v.z - m); v.w = __expf(v.w - m);
    float sum = v.x + v.y + v.z + v.w;
#pragma unroll
    for (int s = 1; s < 64; s <<= 1) sum += __shfl_xor(sum, s, 64);
    float inv = 1.f / sum;
    v.x *= inv; v.y *= inv; v.z *= inv; v.w *= inv;
    rowp[lane] = v;
}

// ---------------------------------------------------------------------------
// K4: out = proj(attn @ np), 8-way acc splits (unchanged)
// ---------------------------------------------------------------------------
__global__ __launch_bounds__(256) void k_out(const float* __restrict__ attn,
                                             const float* __restrict__ np_,
                                             const float* __restrict__ Wt,
                                             const float* __restrict__ bias,
                                             float* __restrict__ out) {
    int bi = blockIdx.x;
    int bb = bi >> 8, ii = bi & 255;
    int d = threadIdx.x;
    __shared__ float at[8 * 256];
    __shared__ float xl[256];
#pragma unroll
    for (int s = 0; s < 2; ++s) {
        int idx = d + s * 256;
        int h = idx >> 6, q = idx & 63;
        ((float4*)at)[idx] =
            ((const float4*)(attn + ((size_t)(bb * 8 + h) * 256 + ii) * 256))[q];
    }
    __syncthreads();
    int h = d >> 5;
    const float* npb = np_ + (size_t)bb * 65536 + d;
    const float* ath = at + h * 256;
    float a[8] = {0.f, 0.f, 0.f, 0.f, 0.f, 0.f, 0.f, 0.f};
#pragma unroll 2
    for (int j = 0; j < 256; j += 8) {
#pragma unroll
        for (int q = 0; q < 8; ++q)
            a[q] = fmaf(ath[j + q], npb[(size_t)(j + q) * 256], a[q]);
    }
    xl[d] = ((a[0] + a[1]) + (a[2] + a[3])) + ((a[4] + a[5]) + (a[6] + a[7]));
    __syncthreads();
    float c[8] = {bias[d], 0.f, 0.f, 0.f, 0.f, 0.f, 0.f, 0.f};
#pragma unroll 2
    for (int k = 0; k < 256; k += 8) {
#pragma unroll
        for (int q = 0; q < 8; ++q)
            c[q] = fmaf(xl[k + q], Wt[(k + q) * 256 + d], c[q]);
    }
    out[bi * 256 + d] =
        ((c[0] + c[1]) + (c[2] + c[3])) + ((c[4] + c[5]) + (c[6] + c[7]));
}

// ---------------------------------------------------------------------------
extern "C" void kernel_launch(void* const* d_in, const int* in_sizes, int n_in,
                              void* d_out, int out_size, void* d_ws, size_t ws_size,
                              hipStream_t stream) {
    (void)in_sizes; (void)n_in; (void)out_size; (void)ws_size;
    const float* nodes = (const float*)d_in[0];
    const float* edges = (const float*)d_in[1];
    const float* W     = (const float*)d_in[2];
    const float* bias  = (const float*)d_in[3];

    float* out  = (float*)d_out;            // (4,256,256)
    float* attn = out + 262144;             // (4,8,256,256)

    float* np_ = (float*)d_ws;              // 262144 floats
    float* Wt  = np_ + 262144;              // 65536 floats
    unsigned short* Whi = (unsigned short*)(Wt + 65536);  // 65536 bf16
    unsigned short* Wlo = Whi + 65536;                    // 65536 bf16

    hipLaunchKernelGGL(k_prep,      dim3(256),  dim3(256), 0, stream, W, Wt, Whi, Wlo);
    hipLaunchKernelGGL(k_node_proj, dim3(1024), dim3(256), 0, stream, nodes, Wt, bias, np_);
    hipLaunchKernelGGL(k_edge_mfma, dim3(4096), dim3(256), 0, stream, edges, Whi, Wlo, bias, np_, attn);
    hipLaunchKernelGGL(k_softmax,   dim3(2048), dim3(256), 0, stream, attn);
    hipLaunchKernelGGL(k_out,       dim3(1024), dim3(256), 0, stream, attn, np_, Wt, bias, out);
}